// Round 2
// baseline (531.718 us; speedup 1.0000x reference)
//
#include <hip/hip_runtime.h>
#include <hip/hip_bf16.h>

#define ENC_DIM 2048
#define DEC_DIM 512
#define ATT_DIM 512
#define BATCH   128
#define NPIX    196
#define NROWS   (BATCH * NPIX)   // 25088

typedef short bf16x8 __attribute__((ext_vector_type(8)));
typedef float f32x4  __attribute__((ext_vector_type(4)));
typedef unsigned short u16x8 __attribute__((ext_vector_type(8)));

__device__ __forceinline__ unsigned short f2bf(float f) {
    union { float f; unsigned u; } v; v.f = f;
    unsigned r = v.u + 0x7fffu + ((v.u >> 16) & 1u);   // RNE
    return (unsigned short)(r >> 16);
}

// native cast (compiler emits v_cvt_pk_bf16_f32 for pairs; RNE, bit-identical to f2bf)
__device__ __forceinline__ unsigned short bfc(float f) {
    union { __hip_bfloat16 h; unsigned short u; } v;
    v.h = __float2bfloat16(f);
    return v.u;
}

// ---------------------------------------------------------------- k0:
// Wtf = W_enc in MFMA-B-fragment order.
// slot = ((s*2 + h)*32 + cg)*64 + lane   (s = kstep of 64 k, h = 32-k half,
// cg = 16-col group, lane = q*16+cl).  Wtf[slot*8 + j] = bf16(W_enc[k+j][a])
// with a = cg*16+cl, k = s*64 + h*32 + q*8.  A wave's B-fragment load in k2
// is then one fully-coalesced global_load_dwordx4 (1 KB).
__global__ void k0_wtfrag(const float* __restrict__ W_enc,
                          unsigned short* __restrict__ Wtf) {
    const int slot = blockIdx.x * 256 + threadIdx.x;   // 512 blocks -> 131072 slots
    const int lane = slot & 63;
    const int cg   = (slot >> 6) & 31;
    const int h    = (slot >> 11) & 1;
    const int s    = slot >> 12;
    const int q = lane >> 4, cl = lane & 15;
    const int a = cg * 16 + cl;
    const int k = s * 64 + h * 32 + q * 8;
    ushort4 u0, u1;
    u0.x = f2bf(W_enc[(size_t)(k + 0) * ATT_DIM + a]);
    u0.y = f2bf(W_enc[(size_t)(k + 1) * ATT_DIM + a]);
    u0.z = f2bf(W_enc[(size_t)(k + 2) * ATT_DIM + a]);
    u0.w = f2bf(W_enc[(size_t)(k + 3) * ATT_DIM + a]);
    u1.x = f2bf(W_enc[(size_t)(k + 4) * ATT_DIM + a]);
    u1.y = f2bf(W_enc[(size_t)(k + 5) * ATT_DIM + a]);
    u1.z = f2bf(W_enc[(size_t)(k + 6) * ATT_DIM + a]);
    u1.w = f2bf(W_enc[(size_t)(k + 7) * ATT_DIM + a]);
    *(ushort4*)&Wtf[(size_t)slot * 8]     = u0;
    *(ushort4*)&Wtf[(size_t)slot * 8 + 4] = u1;
}

// ---------------------------------------------------------------- k1:
// att2'[b][a] = dh[b,:]@W_dec[:,a] + b_dec[a] + b_enc[a];  att[r] = b_full.
// 256 blocks (b x col-half), two d-chains per thread for ILP.
__global__ void k1_att2(const float* __restrict__ dh, const float* __restrict__ W_dec,
                        const float* __restrict__ b_dec, const float* __restrict__ b_enc,
                        const float* __restrict__ b_full,
                        float* __restrict__ att2, float* __restrict__ att) {
    __shared__ float dhs[DEC_DIM];
    const int bid = blockIdx.x, t = threadIdx.x;   // 256 blocks x 256 thr
    const int b = bid >> 1;
    const int c = (bid & 1) * 256 + t;
    dhs[t]       = dh[b * DEC_DIM + t];
    dhs[t + 256] = dh[b * DEC_DIM + t + 256];
    __syncthreads();
    float acc0 = 0.f, acc1 = 0.f;
    #pragma unroll 8
    for (int d = 0; d < 256; ++d) {
        acc0 += dhs[d]       * W_dec[d * ATT_DIM + c];
        acc1 += dhs[d + 256] * W_dec[(d + 256) * ATT_DIM + c];
    }
    att2[b * ATT_DIM + c] = acc0 + acc1 + b_dec[c] + b_enc[c];
    const int gid = bid * 256 + t;
    if (gid < NROWS) att[gid] = b_full[0];
}

// ---------------------------------------------------------------- k2:
// Fused bf16 MFMA GEMM + relu + W_full reduction -> atomic partial scores.
// BM=128, BN=512 (full N), BK=64. 196 blocks x 512 thr (8 waves).
// Wave w owns cols [w*64, w*64+64), all 128 rows: acc[8][4].
// B: NO LDS - fragment loads straight from Wtf (fragment layout, coalesced,
//    L2-resident 2 MB), double-buffered in registers one kstep ahead.
// A: fp32->bf16 reg-staged into double-buffered LDS (stride-72 shorts,
//    conflict-free b128 reads), one barrier per kstep, loads issued a full
//    MFMA-phase ahead.
__launch_bounds__(512, 2)
__global__ void k2_gemm(const float* __restrict__ enc, const unsigned short* __restrict__ Wtf,
                        const float* __restrict__ att2, const float* __restrict__ W_full,
                        float* __restrict__ att) {
    __shared__ __align__(16) unsigned short As0[128 * 72];   // 18432 B
    __shared__ __align__(16) unsigned short As1[128 * 72];   // 18432 B
    __shared__ float att2s[2][ATT_DIM];
    __shared__ float wfs[ATT_DIM];

    const int t    = threadIdx.x;
    const int row0 = blockIdx.x * 128;
    const int b0   = row0 / NPIX;
    const int rows_left = (b0 + 1) * NPIX - row0;

    att2s[0][t] = att2[b0 * ATT_DIM + t];
    att2s[1][t] = (b0 + 1 < BATCH) ? att2[(b0 + 1) * ATT_DIM + t] : 0.f;
    wfs[t]      = W_full[t];

    const int w    = t >> 6;         // wave 0..7: col span w*64
    const int lane = t & 63;
    const int q    = lane >> 4;      // 0..3
    const int cl   = lane & 15;

    // A staging: thread t stages row (t>>2), 16 floats at col (t&3)*16
    const int arow = t >> 2;
    const int acq  = (t & 3) * 16;
    const float* encA = enc + (size_t)(row0 + arow) * ENC_DIM + acq;

    f32x4 acc[8][4] = {};
    bf16x8 bA[2][4], bB[2][4];       // B fragments, explicit double-buffer

    // ---- prologue: stage A[k=0] into As0, load B[k=0] into bA
    {
        const float4 v0 = *(const float4*)(encA + 0);
        const float4 v1 = *(const float4*)(encA + 4);
        const float4 v2 = *(const float4*)(encA + 8);
        const float4 v3 = *(const float4*)(encA + 12);
        u16x8 u0, u1;
        u0[0]=bfc(v0.x); u0[1]=bfc(v0.y); u0[2]=bfc(v0.z); u0[3]=bfc(v0.w);
        u0[4]=bfc(v1.x); u0[5]=bfc(v1.y); u0[6]=bfc(v1.z); u0[7]=bfc(v1.w);
        u1[0]=bfc(v2.x); u1[1]=bfc(v2.y); u1[2]=bfc(v2.z); u1[3]=bfc(v2.w);
        u1[4]=bfc(v3.x); u1[5]=bfc(v3.y); u1[6]=bfc(v3.z); u1[7]=bfc(v3.w);
        *(u16x8*)&As0[arow * 72 + acq]     = u0;
        *(u16x8*)&As0[arow * 72 + acq + 8] = u1;
        #pragma unroll
        for (int h = 0; h < 2; ++h)
            #pragma unroll
            for (int ni = 0; ni < 4; ++ni)
                bA[h][ni] = *(const bf16x8*)&Wtf[(size_t)h * 16384
                                                 + (w * 4 + ni) * 512 + lane * 8];
    }
    __syncthreads();

    // ---- main loop: one barrier per kstep, prefetch A & B one kstep ahead
#define K2_BODY(CURAS, NXTAS, CURB, NXTB, KK, PF)                                   \
    {                                                                               \
        float4 aL0, aL1, aL2, aL3;                                                  \
        if (PF) {                                                                   \
            const float* ap = encA + (KK) + 64;                                     \
            aL0 = *(const float4*)(ap + 0);  aL1 = *(const float4*)(ap + 4);        \
            aL2 = *(const float4*)(ap + 8);  aL3 = *(const float4*)(ap + 12);       \
            const size_t bo = (size_t)((KK) + 64) * 512;                            \
            _Pragma("unroll")                                                       \
            for (int h = 0; h < 2; ++h)                                             \
                _Pragma("unroll")                                                   \
                for (int ni = 0; ni < 4; ++ni)                                      \
                    NXTB[h][ni] = *(const bf16x8*)&Wtf[bo + (size_t)h * 16384       \
                                                       + (w * 4 + ni) * 512         \
                                                       + lane * 8];                 \
        }                                                                           \
        _Pragma("unroll")                                                           \
        for (int h = 0; h < 2; ++h)                                                 \
            _Pragma("unroll")                                                       \
            for (int mi = 0; mi < 8; ++mi) {                                        \
                const bf16x8 af = *(const bf16x8*)&CURAS[(mi * 16 + cl) * 72        \
                                                         + h * 32 + q * 8];         \
                _Pragma("unroll")                                                   \
                for (int ni = 0; ni < 4; ++ni)                                      \
                    acc[mi][ni] = __builtin_amdgcn_mfma_f32_16x16x32_bf16(          \
                        af, CURB[h][ni], acc[mi][ni], 0, 0, 0);                     \
            }                                                                       \
        if (PF) {                                                                   \
            u16x8 u0, u1;                                                           \
            u0[0]=bfc(aL0.x); u0[1]=bfc(aL0.y); u0[2]=bfc(aL0.z); u0[3]=bfc(aL0.w); \
            u0[4]=bfc(aL1.x); u0[5]=bfc(aL1.y); u0[6]=bfc(aL1.z); u0[7]=bfc(aL1.w); \
            u1[0]=bfc(aL2.x); u1[1]=bfc(aL2.y); u1[2]=bfc(aL2.z); u1[3]=bfc(aL2.w); \
            u1[4]=bfc(aL3.x); u1[5]=bfc(aL3.y); u1[6]=bfc(aL3.z); u1[7]=bfc(aL3.w); \
            *(u16x8*)&NXTAS[arow * 72 + acq]     = u0;                              \
            *(u16x8*)&NXTAS[arow * 72 + acq + 8] = u1;                              \
        }                                                                           \
        __syncthreads();                                                            \
    }

    for (int kk = 0; kk < ENC_DIM; kk += 128) {
        K2_BODY(As0, As1, bA, bB, kk, true);
        K2_BODY(As1, As0, bB, bA, kk + 64, (kk + 128 < ENC_DIM));
    }
#undef K2_BODY

    // ---- epilogue: relu(att1 + att2') * W_full, reduce this wave's 64 cols.
    #pragma unroll
    for (int mi = 0; mi < 8; ++mi) {
        float rs[4];
        #pragma unroll
        for (int i = 0; i < 4; ++i) {
            const int lr  = mi * 16 + q * 4 + i;              // local row 0..127
            const int sel = (lr >= rows_left) ? 1 : 0;
            float sum = 0.f;
            #pragma unroll
            for (int ni = 0; ni < 4; ++ni) {
                const int c = w * 64 + ni * 16 + cl;          // global col 0..511
                float v = acc[mi][ni][i] + att2s[sel][c];
                v = fmaxf(v, 0.f);
                sum += v * wfs[c];
            }
            rs[i] = sum;
        }
        #pragma unroll
        for (int o = 1; o < 16; o <<= 1) {
            #pragma unroll
            for (int i = 0; i < 4; ++i) rs[i] += __shfl_xor(rs[i], o);
        }
        if (cl == 0) {
            #pragma unroll
            for (int i = 0; i < 4; ++i) {
                const int r = row0 + mi * 16 + q * 4 + i;
                atomicAdd(&att[r], rs[i]);
            }
        }
    }
}

// ---------------------------------------------------------------- k3:
// softmax over P=196, in place. 128 blocks x 256 thr.
__global__ void k3_softmax(float* __restrict__ att_alpha) {
    __shared__ float red[4];
    const int b = blockIdx.x, t = threadIdx.x;
    const int w = t >> 6, lane = t & 63;
    const float x = (t < NPIX) ? att_alpha[b * NPIX + t] : -INFINITY;
    float m = x;
    #pragma unroll
    for (int o = 32; o >= 1; o >>= 1) m = fmaxf(m, __shfl_xor(m, o));
    if (lane == 0) red[w] = m;
    __syncthreads();
    m = fmaxf(fmaxf(red[0], red[1]), fmaxf(red[2], red[3]));
    const float e = (t < NPIX) ? __expf(x - m) : 0.f;
    float s = e;
    #pragma unroll
    for (int o = 32; o >= 1; o >>= 1) s += __shfl_xor(s, o);
    __syncthreads();
    if (lane == 0) red[w] = s;
    __syncthreads();
    s = red[0] + red[1] + red[2] + red[3];
    if (t < NPIX) att_alpha[b * NPIX + t] = e / s;
}

// ---------------------------------------------------------------- k4:
// awe[b][e] = sum_p alpha[b][p] * enc[b][p][e].
// grid (8 e-chunks, 128 b) x 256 thr = 1024 blocks (16 waves/CU).
// thread (s = t&63, g = t>>6): float4 strip s of 256-float chunk,
// pixels p === g (mod 4), 4 independent accumulators, LDS tree over g.
__global__ void k4_awe(const float* __restrict__ enc, const float* __restrict__ alpha,
                       float* __restrict__ awe) {
    __shared__ float as[NPIX];
    __shared__ f32x4 red[4][64];
    const int b  = blockIdx.y;
    const int t  = threadIdx.x;
    const int s  = t & 63;
    const int g  = t >> 6;
    const int e0 = blockIdx.x * 256 + s * 4;
    if (t < NPIX) as[t] = alpha[b * NPIX + t];
    __syncthreads();
    const float* base = enc + (size_t)b * NPIX * ENC_DIM + e0;
    f32x4 a0 = {}, a1 = {}, a2 = {}, a3 = {};
    int p = g;
    #pragma unroll 4
    for (int it = 0; it < 12; ++it, p += 16) {
        a0 += as[p]      * *(const f32x4*)(base + (size_t)(p)      * ENC_DIM);
        a1 += as[p + 4]  * *(const f32x4*)(base + (size_t)(p + 4)  * ENC_DIM);
        a2 += as[p + 8]  * *(const f32x4*)(base + (size_t)(p + 8)  * ENC_DIM);
        a3 += as[p + 12] * *(const f32x4*)(base + (size_t)(p + 12) * ENC_DIM);
    }
    a0 += as[p] * *(const f32x4*)(base + (size_t)p * ENC_DIM);   // p = g + 192 < 196
    red[g][s] = (a0 + a1) + (a2 + a3);
    __syncthreads();
    if (g == 0) {
        const f32x4 r = (red[0][s] + red[1][s]) + (red[2][s] + red[3][s]);
        *(f32x4*)&awe[(size_t)b * ENC_DIM + e0] = r;
    }
}

// ----------------------------------------------------------------
extern "C" void kernel_launch(void* const* d_in, const int* in_sizes, int n_in,
                              void* d_out, int out_size, void* d_ws, size_t ws_size,
                              hipStream_t stream) {
    const float* enc    = (const float*)d_in[0];   // [128,196,2048]
    const float* dh     = (const float*)d_in[1];   // [128,512]
    const float* W_enc  = (const float*)d_in[2];   // [2048,512]
    const float* b_enc  = (const float*)d_in[3];   // [512]
    const float* W_dec  = (const float*)d_in[4];   // [512,512]
    const float* b_dec  = (const float*)d_in[5];   // [512]
    const float* W_full = (const float*)d_in[6];   // [512]
    const float* b_full = (const float*)d_in[7];   // scalar

    float* awe   = (float*)d_out;                  // [128,2048]
    float* alpha = awe + BATCH * ENC_DIM;          // [128,196]; also score scratch

    // workspace: Wtf bf16 (2 MB) + att2' fp32 (256 KB) = 2.25 MB
    unsigned short* Wtf  = (unsigned short*)d_ws;
    float*          att2 = (float*)((char*)d_ws + (size_t)ATT_DIM * ENC_DIM * 2);

    k0_wtfrag   <<<512,          256, 0, stream>>>(W_enc, Wtf);
    k1_att2     <<<256,          256, 0, stream>>>(dh, W_dec, b_dec, b_enc, b_full, att2, alpha);
    k2_gemm     <<<196,          512, 0, stream>>>(enc, Wtf, att2, W_full, alpha);
    k3_softmax  <<<128,          256, 0, stream>>>(alpha);
    k4_awe      <<<dim3(8, 128), 256, 0, stream>>>(enc, alpha, awe);
}

// Round 3
// 396.067 us; speedup vs baseline: 1.3425x; 1.3425x over previous
//
#include <hip/hip_runtime.h>
#include <hip/hip_bf16.h>

#define ENC_DIM 2048
#define DEC_DIM 512
#define ATT_DIM 512
#define BATCH   128
#define NPIX    196
#define NROWS   (BATCH * NPIX)   // 25088

typedef short bf16x8 __attribute__((ext_vector_type(8)));
typedef float f32x4  __attribute__((ext_vector_type(4)));
typedef unsigned short u16x8 __attribute__((ext_vector_type(8)));

__device__ __forceinline__ unsigned short f2bf(float f) {
    union { float f; unsigned u; } v; v.f = f;
    unsigned r = v.u + 0x7fffu + ((v.u >> 16) & 1u);   // RNE
    return (unsigned short)(r >> 16);
}

__device__ __forceinline__ short bfc(float f) {
    union { __hip_bfloat16 h; short s; } v;
    v.h = __float2bfloat16(f);                          // RNE, = f2bf
    return v.s;
}

// async global->LDS, 16 B per lane; dst is wave-uniform base + lane*16
__device__ __forceinline__ void gload16(const void* g, void* l) {
    __builtin_amdgcn_global_load_lds(
        (const __attribute__((address_space(1))) unsigned int*)g,
        (__attribute__((address_space(3))) unsigned int*)l, 16, 0, 0);
}

// ---------------------------------------------------------------- k0:
// Wt[a][e] = bf16(W_enc[e][a])  (2048x512 -> 512x2048), LDS-tiled transpose.
__global__ void k0_transpose(const float* __restrict__ W_enc,
                             unsigned short* __restrict__ Wt) {
    __shared__ float ts[64][65];
    const int a0 = blockIdx.x * 64;      // grid.x = 8
    const int e0 = blockIdx.y * 64;      // grid.y = 32
    const int tx = threadIdx.x & 15;
    const int ty = threadIdx.x >> 4;     // 16x16 threads
    #pragma unroll
    for (int p = 0; p < 4; ++p) {
        const int e = ty + p * 16;
        const float4 v = *(const float4*)&W_enc[(size_t)(e0 + e) * ATT_DIM + a0 + tx * 4];
        ts[e][tx * 4 + 0] = v.x; ts[e][tx * 4 + 1] = v.y;
        ts[e][tx * 4 + 2] = v.z; ts[e][tx * 4 + 3] = v.w;
    }
    __syncthreads();
    #pragma unroll
    for (int p = 0; p < 4; ++p) {
        const int a = ty + p * 16;
        ushort4 u;
        u.x = f2bf(ts[tx * 4 + 0][a]);
        u.y = f2bf(ts[tx * 4 + 1][a]);
        u.z = f2bf(ts[tx * 4 + 2][a]);
        u.w = f2bf(ts[tx * 4 + 3][a]);
        *(ushort4*)&Wt[(size_t)(a0 + a) * ENC_DIM + e0 + tx * 4] = u;
    }
}

// ---------------------------------------------------------------- k1:
// att2'[b][a] = dh[b,:]@W_dec[:,a] + b_dec[a] + b_enc[a];  score[r] = b_full.
__global__ void k1_att2(const float* __restrict__ dh, const float* __restrict__ W_dec,
                        const float* __restrict__ b_dec, const float* __restrict__ b_enc,
                        const float* __restrict__ b_full,
                        float* __restrict__ att2, float* __restrict__ score) {
    __shared__ float dhs[DEC_DIM];
    const int bid = blockIdx.x, t = threadIdx.x;   // 256 blocks x 256 thr
    const int b = bid >> 1;
    const int c = (bid & 1) * 256 + t;
    dhs[t]       = dh[b * DEC_DIM + t];
    dhs[t + 256] = dh[b * DEC_DIM + t + 256];
    __syncthreads();
    float acc0 = 0.f, acc1 = 0.f;
    #pragma unroll 8
    for (int d = 0; d < 256; ++d) {
        acc0 += dhs[d]       * W_dec[d * ATT_DIM + c];
        acc1 += dhs[d + 256] * W_dec[(d + 256) * ATT_DIM + c];
    }
    att2[b * ATT_DIM + c] = acc0 + acc1 + b_dec[c] + b_enc[c];
    const int gid = bid * 256 + t;
    if (gid < NROWS) score[gid] = b_full[0];
}

// ---------------------------------------------------------------- k2:
// Fused bf16 MFMA GEMM + relu + W_full reduction -> atomic partial scores.
// BM=128, BN=128, BK=64, 4 waves, acc[4][4] (round-1 verified geometry +
// XCD-chunked grid swizzle).  NEW: A staged via global_load_lds as *fp32*
// (async path, no reg round-trip, no ds_write), 16B-granule XOR swizzle
// (slot = G ^ (row&7)) applied on the per-lane GLOBAL source (LDS dest
// linear) and on the fragment reads (both-sides involution).  fp32->bf16
// conversion moves to the read side (cvt_pk, overlaps MFMA).
// Fragment-read banks: slot spans 8 values x 4 banks, 8 lanes each ->
// uniform 32-bank load = conflict-free.  All frag addrs = hoisted lane
// bases + immediate offsets (zero per-kstep addr VALU).
__launch_bounds__(256, 3)
__global__ void k2_gemm(const float* __restrict__ enc, const unsigned short* __restrict__ Wt,
                        const float* __restrict__ att2, const float* __restrict__ W_full,
                        float* __restrict__ score) {
    __shared__ __align__(16) float          Asf[128 * 64];   // 32768 B, linear+swz
    __shared__ __align__(16) unsigned short Bs [128 * 64];   // 16384 B, linear+swz
    __shared__ float att2s[2][128];
    __shared__ float wfs[128];

    const int t = threadIdx.x;
    const int tile = (blockIdx.x & 7) * 98 + (blockIdx.x >> 3);   // bijective on [0,784)
    const int n0   = (tile & 3) * 128;
    const int row0 = (tile >> 2) * 128;
    const int b0   = row0 / NPIX;
    const int rows_left = (b0 + 1) * NPIX - row0;

    if (t < 128) {
        att2s[0][t] = att2[b0 * ATT_DIM + n0 + t];
        att2s[1][t] = (b0 + 1 < BATCH) ? att2[(b0 + 1) * ATT_DIM + n0 + t] : 0.f;
        wfs[t]      = W_full[n0 + t];
    }

    const int w    = t >> 6;         // wave 0..3
    const int lane = t & 63;
    const int q    = lane >> 4;      // 0..3
    const int cl   = lane & 15;
    const int wm   = (w >> 1) * 64;  // wave's row offset (0/64)
    const int wn   = (w & 1) * 64;   // wave's col offset (0/64)

    f32x4 acc[4][4] = {};

    // A staging sources (global_load_lds, fp32, swizzled source):
    // instr i (0..7) covers rows w*32 + i*4 + r4; lane's granule = sl ^ ((i*4+r4)&7)
    const int r4 = lane >> 4;        // 0..3
    const int sl = lane & 15;
    const float* aS0 = enc + (size_t)(row0 + w * 32 + r4)     * ENC_DIM + ((sl ^ r4)       << 2);
    const float* aS1 = enc + (size_t)(row0 + w * 32 + 4 + r4) * ENC_DIM + ((sl ^ (4 + r4)) << 2);

    // B staging source (bf16, swizzled source), round-1 verified
    const int br = lane >> 3;                       // 0..7
    const int bc = ((lane & 7) ^ br) * 8;           // swizzled col (shorts)
    const unsigned short* WtB = Wt + (size_t)(n0 + w * 32 + br) * ENC_DIM + bc;

    // Hoisted A-fragment byte addresses: logical floats k=h*32+q*8.. of row
    // wm+mi*16+cl live at byte  row*256 + ((h*8+q*2(+0/1)) ^ (cl&7))*16
    //  = (row*256 + (cl&7)*16) ^ (q*32) ^ (opt 16)  + h*128 (imm).
    unsigned ab[4], ab2[4];
    #pragma unroll
    for (int mi = 0; mi < 4; ++mi) {
        unsigned base = ((unsigned)(wm + mi * 16 + cl) << 8) + ((unsigned)(cl & 7) << 4);
        base ^= (unsigned)(q << 5);
        ab[mi]  = base;
        ab2[mi] = base ^ 16u;
    }
    const char* Ab = (const char*)Asf;

    for (int kk = 0; kk < ENC_DIM; kk += 64) {
        __syncthreads();   // previous iteration's frag reads complete
        // B: 4 x global_load_lds (8 rows each)
        #pragma unroll
        for (int i = 0; i < 4; ++i)
            gload16(WtB + (size_t)i * 8 * ENC_DIM + kk, &Bs[(w * 32 + i * 8) * 64]);
        // A: 8 x global_load_lds (4 rows each, fp32)
        #pragma unroll
        for (int i = 0; i < 4; ++i) {
            gload16(aS0 + (size_t)i * 8 * ENC_DIM + kk, &Asf[(w * 32 + i * 8)     * 64]);
            gload16(aS1 + (size_t)i * 8 * ENC_DIM + kk, &Asf[(w * 32 + i * 8 + 4) * 64]);
        }
        __syncthreads();   // tile visible (barrier drains vmcnt)

        #pragma unroll
        for (int h = 0; h < 2; ++h) {   // two 32-wide K halves
            bf16x8 af[4], bfr[4];
            #pragma unroll
            for (int mi = 0; mi < 4; ++mi) {
                const f32x4 fa = *(const f32x4*)(Ab + ab[mi]  + h * 128);
                const f32x4 fb = *(const f32x4*)(Ab + ab2[mi] + h * 128);
                bf16x8 u;
                u[0] = bfc(fa[0]); u[1] = bfc(fa[1]); u[2] = bfc(fa[2]); u[3] = bfc(fa[3]);
                u[4] = bfc(fb[0]); u[5] = bfc(fb[1]); u[6] = bfc(fb[2]); u[7] = bfc(fb[3]);
                af[mi] = u;
            }
            #pragma unroll
            for (int i = 0; i < 4; ++i)
                bfr[i] = *(const bf16x8*)&Bs[(wn + i * 16 + cl) * 64
                                             + (((h * 4 + q) ^ (cl & 7)) * 8)];
            #pragma unroll
            for (int mi = 0; mi < 4; ++mi)
                #pragma unroll
                for (int ni = 0; ni < 4; ++ni)
                    acc[mi][ni] = __builtin_amdgcn_mfma_f32_16x16x32_bf16(
                        af[mi], bfr[ni], acc[mi][ni], 0, 0, 0);
        }
    }

    // Epilogue: relu(att1 + att2') * W_full, reduce over this block's 128 cols.
    #pragma unroll
    for (int mi = 0; mi < 4; ++mi) {
        float rs[4];
        #pragma unroll
        for (int i = 0; i < 4; ++i) {
            const int lr  = wm + mi * 16 + q * 4 + i;         // local row
            const int sel = (lr >= rows_left) ? 1 : 0;
            float sum = 0.f;
            #pragma unroll
            for (int ni = 0; ni < 4; ++ni) {
                const int j = wn + ni * 16 + cl;              // local col 0..127
                float v = acc[mi][ni][i] + att2s[sel][j];
                v = fmaxf(v, 0.f);
                sum += v * wfs[j];
            }
            rs[i] = sum;
        }
        #pragma unroll
        for (int o = 1; o < 16; o <<= 1) {
            #pragma unroll
            for (int i = 0; i < 4; ++i) rs[i] += __shfl_xor(rs[i], o);
        }
        if (cl == 0) {
            #pragma unroll
            for (int i = 0; i < 4; ++i) {
                const int r = row0 + wm + mi * 16 + q * 4 + i;
                atomicAdd(&score[r], rs[i]);
            }
        }
    }
}

// ---------------------------------------------------------------- k4:
// Fused softmax + awe.  grid (8 e-chunks, 128 b) x 256 thr.
// Each block computes softmax over score[b][0..195] locally (redundant 8x,
// cheap); block x==0 writes alpha; then weighted sum over pixels.
__global__ void k4_awe(const float* __restrict__ enc, const float* __restrict__ score,
                       float* __restrict__ alpha, float* __restrict__ awe) {
    __shared__ float as[NPIX];
    __shared__ float red[4];
    __shared__ f32x4 redv[4][64];
    const int b  = blockIdx.y;
    const int t  = threadIdx.x;
    const int wv = t >> 6, lane = t & 63;
    // --- softmax over P=196 ---
    const float x = (t < NPIX) ? score[b * NPIX + t] : -INFINITY;
    float m = x;
    #pragma unroll
    for (int o = 32; o >= 1; o >>= 1) m = fmaxf(m, __shfl_xor(m, o));
    if (lane == 0) red[wv] = m;
    __syncthreads();
    m = fmaxf(fmaxf(red[0], red[1]), fmaxf(red[2], red[3]));
    const float e = (t < NPIX) ? __expf(x - m) : 0.f;
    float s = e;
    #pragma unroll
    for (int o = 32; o >= 1; o >>= 1) s += __shfl_xor(s, o);
    __syncthreads();
    if (lane == 0) red[wv] = s;
    __syncthreads();
    s = red[0] + red[1] + red[2] + red[3];
    const float a = e / s;
    if (t < NPIX) {
        as[t] = a;
        if (blockIdx.x == 0) alpha[b * NPIX + t] = a;
    }
    __syncthreads();
    // --- awe: thread (s=lane, g=wv): float4 strip, pixels p === g (mod 4) ---
    const int e0 = blockIdx.x * 256 + lane * 4;
    const float* base = enc + (size_t)b * NPIX * ENC_DIM + e0;
    f32x4 a0 = {}, a1 = {}, a2 = {}, a3 = {};
    int p = wv;
    #pragma unroll 4
    for (int it = 0; it < 12; ++it, p += 16) {
        a0 += as[p]      * *(const f32x4*)(base + (size_t)(p)      * ENC_DIM);
        a1 += as[p + 4]  * *(const f32x4*)(base + (size_t)(p + 4)  * ENC_DIM);
        a2 += as[p + 8]  * *(const f32x4*)(base + (size_t)(p + 8)  * ENC_DIM);
        a3 += as[p + 12] * *(const f32x4*)(base + (size_t)(p + 12) * ENC_DIM);
    }
    a0 += as[p] * *(const f32x4*)(base + (size_t)p * ENC_DIM);   // p = wv + 192 < 196
    redv[wv][lane] = (a0 + a1) + (a2 + a3);
    __syncthreads();
    if (wv == 0) {
        const f32x4 r = (redv[0][lane] + redv[1][lane]) + (redv[2][lane] + redv[3][lane]);
        *(f32x4*)&awe[(size_t)b * ENC_DIM + e0] = r;
    }
}

// ----------------------------------------------------------------
extern "C" void kernel_launch(void* const* d_in, const int* in_sizes, int n_in,
                              void* d_out, int out_size, void* d_ws, size_t ws_size,
                              hipStream_t stream) {
    const float* enc    = (const float*)d_in[0];   // [128,196,2048]
    const float* dh     = (const float*)d_in[1];   // [128,512]
    const float* W_enc  = (const float*)d_in[2];   // [2048,512]
    const float* b_enc  = (const float*)d_in[3];   // [512]
    const float* W_dec  = (const float*)d_in[4];   // [512,512]
    const float* b_dec  = (const float*)d_in[5];   // [512]
    const float* W_full = (const float*)d_in[6];   // [512]
    const float* b_full = (const float*)d_in[7];   // scalar

    float* awe   = (float*)d_out;                  // [128,2048]
    float* alpha = awe + BATCH * ENC_DIM;          // [128,196] final output

    // workspace: Wt bf16 (2 MB) + att2' fp32 (256 KB) + raw scores (100 KB)
    unsigned short* Wt    = (unsigned short*)d_ws;
    float*          att2  = (float*)((char*)d_ws + (size_t)ATT_DIM * ENC_DIM * 2);
    float*          score = att2 + (size_t)BATCH * ATT_DIM;

    k0_transpose<<<dim3(8, 32),  256, 0, stream>>>(W_enc, Wt);
    k1_att2     <<<256,          256, 0, stream>>>(dh, W_dec, b_dec, b_enc, b_full, att2, score);
    k2_gemm     <<<784,          256, 0, stream>>>(enc, Wt, att2, W_full, score);
    k4_awe      <<<dim3(8, 128), 256, 0, stream>>>(enc, score, alpha, awe);
}